// Round 7
// baseline (346.543 us; speedup 1.0000x reference)
//
#include <hip/hip_runtime.h>
#include <hip/hip_bf16.h>

typedef short bf8 __attribute__((ext_vector_type(8)));   // 8 bf16 (4 VGPRs)
typedef float f4 __attribute__((ext_vector_type(4)));

#define S_LEN 4096
#define H_DIM 1024
#define D_DIM 512
#define B_DIM 16
#define OUT_BASE ((size_t)B_DIM * S_LEN * H_DIM)

// float -> bf16 bits, round-to-nearest-even
static __device__ __forceinline__ unsigned short f2bf(float f) {
    union { float f; unsigned int u; } c; c.f = f;
    unsigned int u = c.u;
    return (unsigned short)((u + 0x7FFFu + ((u >> 16) & 1u)) >> 16);
}

// cW1 [K=1024][N=512] f32 row-major  ->  wT [N=512][K=1024] bf16
__global__ __launch_bounds__(256) void prep_transpose(const float* __restrict__ cW1,
                                                      unsigned short* __restrict__ wT) {
    __shared__ float tile[64][68];
    const int kt = blockIdx.x >> 3;
    const int nt = blockIdx.x & 7;
    const int tr = threadIdx.x >> 4;
    const int tc = threadIdx.x & 15;
#pragma unroll
    for (int i = 0; i < 4; ++i) {
        const f4 v = *(const f4*)(cW1 + (size_t)(kt * 64 + i * 16 + tr) * D_DIM + nt * 64 + tc * 4);
        tile[i * 16 + tr][tc * 4 + 0] = v.x;
        tile[i * 16 + tr][tc * 4 + 1] = v.y;
        tile[i * 16 + tr][tc * 4 + 2] = v.z;
        tile[i * 16 + tr][tc * 4 + 3] = v.w;
    }
    __syncthreads();
#pragma unroll
    for (int i = 0; i < 4; ++i) {
        const int n = i * 16 + tr;
        ushort4 o;
        o.x = f2bf(tile[tc * 4 + 0][n]);
        o.y = f2bf(tile[tc * 4 + 1][n]);
        o.z = f2bf(tile[tc * 4 + 2][n]);
        o.w = f2bf(tile[tc * 4 + 3][n]);
        *(ushort4*)(wT + (size_t)(nt * 64 + n) * H_DIM + kt * 64 + tc * 4) = o;
    }
}

// Kernel A: GEMM only. Block = one b, 32 consecutive s. Stage 32x1024 f32 -> bf16 LDS
// (64 KB, swizzled f(row,s) = s ^ (row&7) ^ ((s>>3)&7)); barrier-free K-loop, B from
// L2-resident wT. Writes only per-(b,s) sigmoid/16 partials (nt) to ws.
__global__ __launch_bounds__(512, 4) void comp_gemm_kernel(
    const float* __restrict__ states,
    const unsigned short* __restrict__ wT,
    const float* __restrict__ cb1,
    const float* __restrict__ cW2,
    const float* __restrict__ cb2,
    float* __restrict__ part_ws) {
    __shared__ unsigned short As[32][1024];   // 64 KB

    const int t = threadIdx.x;
    const int lane = t & 63;
    const int wv = t >> 6;        // 0..7 : wave n-slice [wv*64, +64)
    const int la = lane & 15;
    const int lg = lane >> 4;
    const int b = blockIdx.x >> 7;
    const int s0 = (blockIdx.x & 127) * 32;
    const size_t base = ((size_t)b * S_LEN + s0) * H_DIM;

    // ---- staging: thread (row = t>>4, c = t&15): 8 slots of 8 floats ----
    const int row = t >> 4;
    const int c = t & 15;
    const int rx = row & 7;
    const float* gp = states + base + (size_t)row * H_DIM + c * 8;
    char* lrow = (char*)&As[0][0] + row * 2048;
#pragma unroll
    for (int i = 0; i < 8; ++i) {
        const f4 v0 = *(const f4*)(gp + i * 128);
        const f4 v1 = *(const f4*)(gp + i * 128 + 4);
        bf8 pk;
        pk[0] = (short)f2bf(v0.x); pk[1] = (short)f2bf(v0.y);
        pk[2] = (short)f2bf(v0.z); pk[3] = (short)f2bf(v0.w);
        pk[4] = (short)f2bf(v1.x); pk[5] = (short)f2bf(v1.y);
        pk[6] = (short)f2bf(v1.z); pk[7] = (short)f2bf(v1.w);
        const int j = i * 16 + c;                       // 16-B slot index 0..127
        const int sl = j ^ rx ^ ((j >> 3) & 7);         // swizzled
        *(bf8*)(lrow + sl * 16) = pk;
    }
    __syncthreads();

    // ---- barrier-free K-loop: A from LDS, B straight from L2 ----
    f4 acc[2][4];
#pragma unroll
    for (int a = 0; a < 2; ++a)
#pragma unroll
        for (int q = 0; q < 4; ++q) acc[a][q] = f4{0.f, 0.f, 0.f, 0.f};

    const unsigned short* bp = wT + (size_t)(wv * 64 + la) * H_DIM + lg * 8;
    bf8 bcur[4];
#pragma unroll
    for (int fc = 0; fc < 4; ++fc)
        bcur[fc] = *(const bf8*)(bp + (size_t)fc * 16 * H_DIM);

#pragma unroll
    for (int ch = 0; ch < 32; ++ch) {
        bf8 bnext[4];
        if (ch < 31) {
#pragma unroll
            for (int fc = 0; fc < 4; ++fc)
                bnext[fc] = *(const bf8*)(bp + (size_t)fc * 16 * H_DIM + (ch + 1) * 32);
        }
        bf8 af[2];
#pragma unroll
        for (int fr = 0; fr < 2; ++fr) {
            const int s = ch * 4 + lg;
            const int sl = s ^ (la & 7) ^ ((s >> 3) & 7);
            af[fr] = *(const bf8*)((char*)&As[0][0] + (fr * 16 + la) * 2048 + sl * 16);
        }
#pragma unroll
        for (int fr = 0; fr < 2; ++fr)
#pragma unroll
            for (int fc = 0; fc < 4; ++fc)
                acc[fr][fc] = __builtin_amdgcn_mfma_f32_16x16x32_bf16(af[fr], bcur[fc], acc[fr][fc], 0, 0, 0);
        if (ch < 31) {
#pragma unroll
            for (int fc = 0; fc < 4; ++fc) bcur[fc] = bnext[fc];
        }
    }

    // ---- epilogue: relu + dot(cW2) + sigmoid/16 -> partial per (b, s) ----
    float w2v[4], b1v[4];
#pragma unroll
    for (int fc = 0; fc < 4; ++fc) {
        const int d = wv * 64 + fc * 16 + la;
        w2v[fc] = cW2[d];
        b1v[fc] = cb1[d];
    }
    __syncthreads();                       // done reading As -> overlay scratch
    float* part = (float*)&As[0][0];       // [32][8]
#pragma unroll
    for (int fr = 0; fr < 2; ++fr) {
#pragma unroll
        for (int rg = 0; rg < 4; ++rg) {
            float p = 0.f;
#pragma unroll
            for (int fc = 0; fc < 4; ++fc)
                p += fmaxf(acc[fr][fc][rg] + b1v[fc], 0.f) * w2v[fc];
#pragma unroll
            for (int off = 1; off < 16; off <<= 1)
                p += __shfl_xor(p, off, 64);   // sum over 16 lane-columns (n)
            if (la == 0) part[(fr * 16 + lg * 4 + rg) * 8 + wv] = p;
        }
    }
    __syncthreads();
    if (t < 32) {
        float sum = cb2[0];
#pragma unroll
        for (int ww = 0; ww < 8; ++ww) sum += part[t * 8 + ww];
        const float sg = 1.f / (1.f + __expf(-sum));
        __builtin_nontemporal_store(sg * (1.f / 16.f), part_ws + (size_t)b * S_LEN + s0 + t);
    }
}

// Kernel B: pure max-occupancy copy states -> out. Non-temporal stores keep states
// resident in L3 (so GEMM reads are L3-hits on replays).
__global__ __launch_bounds__(256) void copy_kernel(const float* __restrict__ states,
                                                   float* __restrict__ out) {
    const size_t tid = (size_t)blockIdx.x * 256 + threadIdx.x;   // 524288 threads
#pragma unroll
    for (int g = 0; g < 4; ++g) {
        f4 v[8];
#pragma unroll
        for (int i = 0; i < 8; ++i)
            v[i] = *(const f4*)(states + 4 * (tid + (size_t)(g * 8 + i) * 524288));
#pragma unroll
        for (int i = 0; i < 8; ++i)
            __builtin_nontemporal_store(v[i], (f4*)(out + 4 * (tid + (size_t)(g * 8 + i) * 524288)));
    }
}

// comp_mean[s] = sum_b partial[b][s]; steps_used ≡ 1 (rb<=128-t can never make
// trunc(rb/(S-t+1))>=2; negative rb clips to 1); rb_final = 128-4096 = -3968.
__global__ __launch_bounds__(256) void reduce_comp(const float* __restrict__ part_ws,
                                                   float* __restrict__ out) {
    const int s = blockIdx.x * 256 + threadIdx.x;
    float sum = 0.f;
#pragma unroll
    for (int b = 0; b < B_DIM; ++b) sum += part_ws[(size_t)b * S_LEN + s];
    __builtin_nontemporal_store(sum, out + OUT_BASE + S_LEN + s);    // comp_mean
    __builtin_nontemporal_store(1.0f, out + OUT_BASE + s);           // steps_used
    if (s == 0) __builtin_nontemporal_store(-3968.0f, out + OUT_BASE + 2 * S_LEN);
}

extern "C" void kernel_launch(void* const* d_in, const int* in_sizes, int n_in,
                              void* d_out, int out_size, void* d_ws, size_t ws_size,
                              hipStream_t stream) {
    const float* states = (const float*)d_in[0];
    const float* cW1 = (const float*)d_in[5];
    const float* cb1 = (const float*)d_in[6];
    const float* cW2 = (const float*)d_in[7];
    const float* cb2 = (const float*)d_in[8];
    float* out = (float*)d_out;
    unsigned short* wT = (unsigned short*)d_ws;                 // 1 MB bf16 [512][1024]
    float* part_ws = (float*)((char*)d_ws + (size_t)D_DIM * H_DIM * 2);  // 256 KB [16][4096]

    hipLaunchKernelGGL(prep_transpose, dim3(128), dim3(256), 0, stream, cW1, wT);
    hipLaunchKernelGGL(comp_gemm_kernel, dim3(2048), dim3(512), 0, stream,
                       states, wT, cb1, cW2, cb2, part_ws);
    hipLaunchKernelGGL(copy_kernel, dim3(2048), dim3(256), 0, stream, states, out);
    hipLaunchKernelGGL(reduce_comp, dim3(16), dim3(256), 0, stream, part_ws, out);
}

// Round 8
// 193.000 us; speedup vs baseline: 1.7956x; 1.7956x over previous
//
#include <hip/hip_runtime.h>
#include <hip/hip_bf16.h>

typedef short bf8 __attribute__((ext_vector_type(8)));   // 8 bf16 (4 VGPRs)
typedef float f4 __attribute__((ext_vector_type(4)));
typedef const __attribute__((address_space(1))) void* gvp;
typedef __attribute__((address_space(3))) void* lvp;

#define S_LEN 4096
#define H_DIM 1024
#define D_DIM 512
#define B_DIM 16
#define OUT_BASE ((size_t)B_DIM * S_LEN * H_DIM)

// float -> bf16 bits, round-to-nearest-even
static __device__ __forceinline__ unsigned short f2bf(float f) {
    union { float f; unsigned int u; } c; c.f = f;
    unsigned int u = c.u;
    return (unsigned short)((u + 0x7FFFu + ((u >> 16) & 1u)) >> 16);
}

// cW1 [K=1024][N=512] f32 row-major -> wT[n][c][sl] bf16, 32-k chunks c, 4 slots/chunk,
// PRE-SWIZZLED: slot sl holds data k-slot (sl ^ (n&3)) so GEMM's linear global_load_lds
// + swizzled ds_read recovers k-slot lg (rule: swizzle both sides or neither).
__global__ __launch_bounds__(256) void prep_transpose(const float* __restrict__ cW1,
                                                      unsigned short* __restrict__ wT) {
    __shared__ float tile[64][68];
    const int kt = blockIdx.x >> 3;   // 16 tiles of 64 k
    const int nt = blockIdx.x & 7;    // 8 tiles of 64 n
    const int tr = threadIdx.x >> 4;
    const int tc = threadIdx.x & 15;
#pragma unroll
    for (int i = 0; i < 4; ++i) {
        const f4 v = *(const f4*)(cW1 + (size_t)(kt * 64 + i * 16 + tr) * D_DIM + nt * 64 + tc * 4);
        tile[i * 16 + tr][tc * 4 + 0] = v.x;
        tile[i * 16 + tr][tc * 4 + 1] = v.y;
        tile[i * 16 + tr][tc * 4 + 2] = v.z;
        tile[i * 16 + tr][tc * 4 + 3] = v.w;
    }
    __syncthreads();
    const int n_local = threadIdx.x & 63;
    const int q = threadIdx.x >> 6;        // 0..3
    const int n = nt * 64 + n_local;
    char* wTb = (char*)wT;
#pragma unroll
    for (int h = q; h < 8; h += 4) {       // 8 slot-units per n per 64k-tile
        const int c_local = h >> 2;        // 0..1 (32-k chunk within tile)
        const int sl = h & 3;
        const int j = sl ^ (n & 3);        // data k-slot
        const int k0 = c_local * 32 + j * 8;
        bf8 pk;
#pragma unroll
        for (int i = 0; i < 8; ++i) pk[i] = (short)f2bf(tile[k0 + i][n_local]);
        *(bf8*)(wTb + (size_t)n * 2048 + (kt * 2 + c_local) * 64 + sl * 16) = pk;
    }
}

// GEMM: M=128 (one b, 128 s) x N=512, BK=32, 32 chunks. A+B double-buffered in 80 KB LDS.
// B staged via global_load_lds from L2-resident pre-swizzled wT; A reg-staged (f32->bf16)
// with swizzled ds_write. Counted s_waitcnt vmcnt(2) per chunk (A-prefetch stays in
// flight); single s_barrier per chunk; no full drain in the main loop.
__global__ __launch_bounds__(512, 2) void comp_gemm_kernel(
    const float* __restrict__ states,
    const unsigned short* __restrict__ wT,
    const float* __restrict__ cb1,
    const float* __restrict__ cW2,
    const float* __restrict__ cb2,
    float* __restrict__ part_ws) {
    __shared__ alignas(16) char lds[81920];   // A [2][8192] @0, B [2][32768] @16384
    char* ldsA = lds;
    char* ldsB = lds + 16384;

    const int t = threadIdx.x;
    const int lane = t & 63;
    const int wv = t >> 6;        // 0..7
    const int wm = wv >> 2;       // 0..1 : rows [wm*64, +64)
    const int wn = wv & 3;        // 0..3 : cols [wn*128, +128)
    const int la = lane & 15;
    const int lg = lane >> 4;
    const int b = blockIdx.x >> 5;
    const int s0 = (blockIdx.x & 31) * 128;

    // A staging: thread -> (row = t>>2, kq = t&3), one 16B bf16 slot per chunk
    const int arow = t >> 2;
    const int kq = t & 3;
    const float* srcA = states + ((size_t)b * S_LEN + s0 + arow) * H_DIM + kq * 8;
    char* dstA = ldsA + arow * 64 + ((kq ^ (arow & 3)) * 16);

    // B staging: 4 global_load_lds(16B/lane) per chunk, linear dest, pre-swizzled src
    const char* srcB = (const char*)wT + (size_t)(wv * 16 + (lane >> 2)) * 2048 + (lane & 3) * 16;
    char* dstB = ldsB + (wv * 16) * 64 + lane * 16;

    f4 acc[4][8];
#pragma unroll
    for (int a = 0; a < 4; ++a)
#pragma unroll
        for (int c = 0; c < 8; ++c) acc[a][c] = f4{0.f, 0.f, 0.f, 0.f};

    auto issueB = [&](int nb_, int ck_) {
#pragma unroll
        for (int i = 0; i < 4; ++i)
            __builtin_amdgcn_global_load_lds((gvp)(srcB + (size_t)i * 128 * 2048 + ck_ * 64),
                                             (lvp)(dstB + nb_ * 32768 + i * 8192), 16, 0, 0);
    };
    auto writeA = [&](int nb_, const f4 a0, const f4 a1) {
        bf8 pk;
        pk[0] = (short)f2bf(a0.x); pk[1] = (short)f2bf(a0.y);
        pk[2] = (short)f2bf(a0.z); pk[3] = (short)f2bf(a0.w);
        pk[4] = (short)f2bf(a1.x); pk[5] = (short)f2bf(a1.y);
        pk[6] = (short)f2bf(a1.z); pk[7] = (short)f2bf(a1.w);
        *(bf8*)(dstA + nb_ * 8192) = pk;
    };

    // ---- prologue: A(0)+B(0) -> buf0; A(1) -> regs ----
    f4 qa0 = *(const f4*)(srcA);
    f4 qa1 = *(const f4*)(srcA + 4);
    issueB(0, 0);
    asm volatile("s_waitcnt vmcnt(4)" ::: "memory");   // A(0) regs ready, B(0) in flight
    __builtin_amdgcn_sched_barrier(0);
    writeA(0, qa0, qa1);
    qa0 = *(const f4*)(srcA + 32);
    qa1 = *(const f4*)(srcA + 36);
    asm volatile("s_waitcnt vmcnt(2) lgkmcnt(0)" ::: "memory");  // B(0) landed; A(1) flying
    __builtin_amdgcn_sched_barrier(0);
    __builtin_amdgcn_s_barrier();
    __builtin_amdgcn_sched_barrier(0);

    const int slo = (lg ^ (la & 3)) * 16;
    const char* arb = ldsA + (wm * 64 + la) * 64 + slo;    // + fr*1024 + buf*8192
    const char* brb = ldsB + (wn * 128 + la) * 64 + slo;   // + fc*1024 + buf*32768

    int buf = 0;
#pragma unroll 1
    for (int ck = 0; ck < 32; ++ck) {
        const int nb = buf ^ 1;
        if (ck < 31) {
            writeA(nb, qa0, qa1);            // stage A(ck+1) (auto-waits its 2 loads)
            issueB(nb, ck + 1);              // B(ck+1): 4 glds, full chunk of slack
            __builtin_amdgcn_sched_barrier(0);  // pin issue order: B before A-prefetch
        }
        f4 na0, na1;
        if (ck < 30) {
            na0 = *(const f4*)(srcA + (ck + 2) * 32);
            na1 = *(const f4*)(srcA + (ck + 2) * 32 + 4);
        }
        bf8 af[4], bv[8];
#pragma unroll
        for (int fr = 0; fr < 4; ++fr)
            af[fr] = *(const bf8*)(arb + buf * 8192 + fr * 1024);
#pragma unroll
        for (int fc = 0; fc < 8; ++fc)
            bv[fc] = *(const bf8*)(brb + buf * 32768 + fc * 1024);
#pragma unroll
        for (int fr = 0; fr < 4; ++fr)
#pragma unroll
            for (int fc = 0; fc < 8; ++fc)
                acc[fr][fc] = __builtin_amdgcn_mfma_f32_16x16x32_bf16(af[fr], bv[fc], acc[fr][fc], 0, 0, 0);
        if (ck < 31) {
            if (ck < 30) { asm volatile("s_waitcnt vmcnt(2) lgkmcnt(0)" ::: "memory"); }
            else         { asm volatile("s_waitcnt vmcnt(0) lgkmcnt(0)" ::: "memory"); }
            __builtin_amdgcn_sched_barrier(0);
            __builtin_amdgcn_s_barrier();
            __builtin_amdgcn_sched_barrier(0);
            if (ck < 30) { qa0 = na0; qa1 = na1; }
            buf = nb;
        }
    }

    // ---- epilogue: relu + dot(cW2) + sigmoid/16 -> partial per (b, s) ----
    float w2v[8], b1v[8];
#pragma unroll
    for (int fc = 0; fc < 8; ++fc) {
        const int d = wn * 128 + fc * 16 + la;
        w2v[fc] = cW2[d];
        b1v[fc] = cb1[d];
    }
    float* part = (float*)lds;    // [128][4] overlays A-b0 (not read since ck30 barrier)
#pragma unroll
    for (int fr = 0; fr < 4; ++fr) {
#pragma unroll
        for (int rg = 0; rg < 4; ++rg) {
            float p = 0.f;
#pragma unroll
            for (int fc = 0; fc < 8; ++fc)
                p += fmaxf(acc[fr][fc][rg] + b1v[fc], 0.f) * w2v[fc];
#pragma unroll
            for (int off = 1; off < 16; off <<= 1)
                p += __shfl_xor(p, off, 64);   // sum over 16 lane-columns (n)
            if (la == 0) part[(wm * 64 + fr * 16 + lg * 4 + rg) * 4 + wn] = p;
        }
    }
    __syncthreads();
    if (t < 128) {
        float sum = cb2[0] + part[t * 4 + 0] + part[t * 4 + 1] + part[t * 4 + 2] + part[t * 4 + 3];
        const float sg = 1.f / (1.f + __expf(-sum));
        __builtin_nontemporal_store(sg * (1.f / 16.f), part_ws + (size_t)b * S_LEN + s0 + t);
    }
}

// Pure max-occupancy copy states -> out (proven ~fast in R7).
__global__ __launch_bounds__(256) void copy_kernel(const float* __restrict__ states,
                                                   float* __restrict__ out) {
    const size_t tid = (size_t)blockIdx.x * 256 + threadIdx.x;   // 524288 threads
#pragma unroll
    for (int g = 0; g < 4; ++g) {
        f4 v[8];
#pragma unroll
        for (int i = 0; i < 8; ++i)
            v[i] = *(const f4*)(states + 4 * (tid + (size_t)(g * 8 + i) * 524288));
#pragma unroll
        for (int i = 0; i < 8; ++i)
            __builtin_nontemporal_store(v[i], (f4*)(out + 4 * (tid + (size_t)(g * 8 + i) * 524288)));
    }
}

// comp_mean[s] = sum_b partial[b][s]; steps_used ≡ 1 (rb<=128-t can never make
// trunc(rb/(S-t+1))>=2; negative rb clips to 1); rb_final = 128-4096 = -3968.
__global__ __launch_bounds__(256) void reduce_comp(const float* __restrict__ part_ws,
                                                   float* __restrict__ out) {
    const int s = blockIdx.x * 256 + threadIdx.x;
    float sum = 0.f;
#pragma unroll
    for (int b = 0; b < B_DIM; ++b) sum += part_ws[(size_t)b * S_LEN + s];
    __builtin_nontemporal_store(sum, out + OUT_BASE + S_LEN + s);    // comp_mean
    __builtin_nontemporal_store(1.0f, out + OUT_BASE + s);           // steps_used
    if (s == 0) __builtin_nontemporal_store(-3968.0f, out + OUT_BASE + 2 * S_LEN);
}

extern "C" void kernel_launch(void* const* d_in, const int* in_sizes, int n_in,
                              void* d_out, int out_size, void* d_ws, size_t ws_size,
                              hipStream_t stream) {
    const float* states = (const float*)d_in[0];
    const float* cW1 = (const float*)d_in[5];
    const float* cb1 = (const float*)d_in[6];
    const float* cW2 = (const float*)d_in[7];
    const float* cb2 = (const float*)d_in[8];
    float* out = (float*)d_out;
    unsigned short* wT = (unsigned short*)d_ws;                 // 1 MB bf16, pre-swizzled
    float* part_ws = (float*)((char*)d_ws + (size_t)D_DIM * H_DIM * 2);  // 256 KB [16][4096]

    hipLaunchKernelGGL(prep_transpose, dim3(128), dim3(256), 0, stream, cW1, wT);
    hipLaunchKernelGGL(comp_gemm_kernel, dim3(512), dim3(512), 0, stream,
                       states, wT, cb1, cW2, cb2, part_ws);
    hipLaunchKernelGGL(copy_kernel, dim3(2048), dim3(256), 0, stream, states, out);
    hipLaunchKernelGGL(reduce_comp, dim3(16), dim3(256), 0, stream, part_ws, out);
}